// Round 15
// baseline (326.595 us; speedup 1.0000x reference)
//
#include <hip/hip_runtime.h>

// FEM stiffness matvec KU = sum_e scatter(K_type(e) @ gather(U, e)).
//
// Round 15 = R14 + two independent, theory-backed changes:
//  (K1) IN-BLOCK counting sort by type (2048 elems, 64 bins, pure LDS,
//       no extra dispatches): waves become type-uniform, so the 144
//       ds_read_b128 filter reads per elem-wave turn into same-address
//       broadcasts (R14 counters: 6.7 extra conflict cyc/read from random
//       t over 8 bank-quads). Permuted nodIdx/types reads stay inside a
//       64 KB window (L1/L2-hot).
//  (K2) 4x-batched record pair-loads: 4 independent nuint4 loads in
//       flight per thread before any LDS atomic. Theory: K2 (~50 us, im-
//       mune to all throughput knobs) is cross-XCD latency-bound on record
//       fetch (~700 cyc, ~2 blocks/CU) — raise MLP, not throughput.
// Carries (verified): fp32 LDS filters stride 580 b128; EPT=2 early Ub
// gathers; bf16-packed U; 8 B bf16 records; RNODES 2048 / MAXB 512;
// block-aggregated tail reservation; pack kernel zeroes KU+tails;
// launch_bounds (1024,4) — R10: VGPR starvation => spill disaster.

#define NTYPES    64
#define KSTRIDE   580            // fp32 words per type: 2320 B, 16 B-aligned
#define RSHIFT    11
#define RNODES    2048
#define MAXB      512
#define CAP       10240          // mean 8180/bucket, +22 sigma slack (even)
#define K1_TPB    1024
#define K1_EPT    2
#define K1_CHUNK  (K1_TPB * K1_EPT)   // 2048
#define K2_TPB    256
#define PREP_TPB  256

typedef int          nint4  __attribute__((ext_vector_type(4)));
typedef unsigned int nuint2 __attribute__((ext_vector_type(2)));
typedef unsigned int nuint4 __attribute__((ext_vector_type(4)));

__device__ __forceinline__ unsigned bf16_rne(float f) {
    unsigned b = __float_as_uint(f);
    return (b + 0x7FFFu + ((b >> 16) & 1u)) >> 16;
}

// ---- phase 0: pack U -> bf16 triples; zero KU and tails -------------------

__global__ __launch_bounds__(PREP_TPB) void pack_u_kernel(
    const float* __restrict__ U, nuint2* __restrict__ Ub,
    float* __restrict__ KU, unsigned* __restrict__ tails,
    int n_nodes, int n_buckets)
{
    int n = blockIdx.x * PREP_TPB + threadIdx.x;
    if (n < n_buckets) tails[n] = 0;
    if (n >= n_nodes) return;
    const float* up = U + (size_t)n * 3;
    unsigned bx = bf16_rne(up[0]);
    unsigned by = bf16_rne(up[1]);
    unsigned bz = bf16_rne(up[2]);
    nuint2 v = { bx | (by << 16), bz };
    Ub[n] = v;
    KU[3 * n + 0] = 0.f;
    KU[3 * n + 1] = 0.f;
    KU[3 * n + 2] = 0.f;
}

// ---- phase 1: compute + bin ----------------------------------------------

__global__ __launch_bounds__(K1_TPB, 4) void feconv_bin_kernel(
    const nuint2* __restrict__ Ub,      // [N] packed bf16 x,y,z
    const float* __restrict__ K,        // [64, 24, 24]
    const int*   __restrict__ types,    // [E]
    const int*   __restrict__ nodIdx,   // [E, 8]
    float*       __restrict__ KU,       // overflow fallback only
    unsigned*    __restrict__ tails,    // [n_buckets]
    nuint2*      __restrict__ recs,     // [n_buckets * CAP]
    int n_elems, int n_buckets)
{
    extern __shared__ float sK[];            // 148,480 B filters
    __shared__ unsigned       sCnt[MAXB];    // 2 KB
    __shared__ unsigned       sBase[MAXB];   // 2 KB
    __shared__ unsigned short sPerm[K1_CHUNK]; // 4 KB type-sorted local ids
    __shared__ unsigned       sTCnt[NTYPES + 1];  // 65 bins (64 = invalid)
    __shared__ unsigned       sTBase[NTYPES + 1];

    const int tid = threadIdx.x;
    const int blockBase = blockIdx.x * K1_CHUNK;

    for (int w = tid; w < NTYPES * 576; w += K1_TPB) {
        int t = w / 576;
        int r = w - t * 576;
        sK[t * KSTRIDE + r] = K[w];
    }
    for (int i = tid; i < n_buckets; i += K1_TPB) sCnt[i] = 0;
    if (tid <= NTYPES) sTCnt[tid] = 0;
    __syncthreads();

    // ---- local counting sort by type (64 bins) ---------------------------
    int tloc[K1_EPT];
#pragma unroll
    for (int k = 0; k < K1_EPT; ++k) {
        int li = k * K1_TPB + tid;
        int e  = blockBase + li;
        tloc[k] = (e < n_elems) ? __builtin_nontemporal_load(&types[e]) : NTYPES;
        atomicAdd(&sTCnt[tloc[k]], 1u);
    }
    __syncthreads();
    if (tid == 0) {                      // 65-bin exclusive scan
        unsigned s = 0;
#pragma unroll
        for (int t = 0; t <= NTYPES; ++t) { sTBase[t] = s; s += sTCnt[t]; }
    }
    __syncthreads();
#pragma unroll
    for (int k = 0; k < K1_EPT; ++k) {
        unsigned pos = atomicAdd(&sTBase[tloc[k]], 1u);  // base doubles as cursor
        sPerm[pos] = (unsigned short)(k * K1_TPB + tid);
    }
    __syncthreads();

    // ---- pass A: permuted connectivity + EARLY gathers + bucket counts ---
    int     nodes[K1_EPT][8];
    int     tt[K1_EPT];
    nuint2  uu[K1_EPT][8];
#pragma unroll
    for (int k = 0; k < K1_EPT; ++k) {
        int li = sPerm[k * K1_TPB + tid];
        int e  = blockBase + li;
        tt[k] = -1;
        if (e < n_elems) {
            tt[k] = types[e];            // L1/L2-hot 64 KB window
            const nint4* q = (const nint4*)(nodIdx + (size_t)e * 8);
            nint4 a = q[0];
            nint4 b = q[1];
            nodes[k][0] = a.x; nodes[k][1] = a.y; nodes[k][2] = a.z; nodes[k][3] = a.w;
            nodes[k][4] = b.x; nodes[k][5] = b.y; nodes[k][6] = b.z; nodes[k][7] = b.w;
#pragma unroll
            for (int j = 0; j < 8; ++j)
                uu[k][j] = Ub[nodes[k][j]];          // issue all 16 gathers now
#pragma unroll
            for (int j = 0; j < 8; ++j)
                atomicAdd(&sCnt[(unsigned)nodes[k][j] >> RSHIFT], 1u);
        }
    }
    __syncthreads();

    // ---- pass B: one global tail reservation per (block, bucket) ---------
    for (int b = tid; b < n_buckets; b += K1_TPB) {
        unsigned c = sCnt[b];
        sBase[b] = c ? atomicAdd(&tails[b], c) : 0u;
        sCnt[b] = 0;                     // reuse as local cursor
    }
    __syncthreads();

    // ---- pass C: unpack, matvec (type-uniform waves -> b128 broadcast) ---
#pragma unroll
    for (int k = 0; k < K1_EPT; ++k) {
        if (tt[k] < 0) continue;

        float ue[24];
#pragma unroll
        for (int j = 0; j < 8; ++j) {
            nuint2 v = uu[k][j];
            ue[3 * j + 0] = __uint_as_float(v.x << 16);
            ue[3 * j + 1] = __uint_as_float(v.x & 0xFFFF0000u);
            ue[3 * j + 2] = __uint_as_float(v.y << 16);
        }

        const float4* Kt4 = (const float4*)(sK + tt[k] * KSTRIDE);
#pragma unroll
        for (int j = 0; j < 8; ++j) {
            float a0 = 0.f, a1 = 0.f, a2 = 0.f;
#pragma unroll
            for (int q = 0; q < 6; ++q) {
                float4 k0 = Kt4[(3 * j + 0) * 6 + q];
                float4 k1 = Kt4[(3 * j + 1) * 6 + q];
                float4 k2 = Kt4[(3 * j + 2) * 6 + q];
                float u0 = ue[4 * q + 0], u1 = ue[4 * q + 1];
                float u2 = ue[4 * q + 2], u3 = ue[4 * q + 3];
                a0 += k0.x * u0 + k0.y * u1 + k0.z * u2 + k0.w * u3;
                a1 += k1.x * u0 + k1.y * u1 + k1.z * u2 + k1.w * u3;
                a2 += k2.x * u0 + k2.y * u1 + k2.z * u2 + k2.w * u3;
            }
            unsigned n = (unsigned)nodes[k][j];
            unsigned b = n >> RSHIFT;
            unsigned pos = sBase[b] + atomicAdd(&sCnt[b], 1u);
            if (pos < CAP) {
                unsigned local = n & (RNODES - 1);
                nuint2 r = { bf16_rne(a0) | (bf16_rne(a1) << 16),
                             bf16_rne(a2) | (local << 16) };
                recs[(size_t)b * CAP + pos] = r;
            } else {  // statistically unreachable; absolute correctness
                atomicAdd(&KU[(size_t)n * 3 + 0], a0);
                atomicAdd(&KU[(size_t)n * 3 + 1], a1);
                atomicAdd(&KU[(size_t)n * 3 + 2], a2);
            }
        }
    }
}

// ---- phase 2: accumulate per bucket --------------------------------------

__device__ __forceinline__ void scatter_pair(float* sAcc, nuint4 p) {
    unsigned o0 = (p.y >> 16) * 3;
    atomicAdd(&sAcc[o0 + 0], __uint_as_float(p.x << 16));
    atomicAdd(&sAcc[o0 + 1], __uint_as_float(p.x & 0xFFFF0000u));
    atomicAdd(&sAcc[o0 + 2], __uint_as_float(p.y << 16));
    unsigned o1 = (p.w >> 16) * 3;
    atomicAdd(&sAcc[o1 + 0], __uint_as_float(p.z << 16));
    atomicAdd(&sAcc[o1 + 1], __uint_as_float(p.z & 0xFFFF0000u));
    atomicAdd(&sAcc[o1 + 2], __uint_as_float(p.w << 16));
}

__global__ __launch_bounds__(K2_TPB) void feconv_acc_kernel(
    const nuint2*   __restrict__ recs,
    const unsigned* __restrict__ tails,
    float*          __restrict__ KU,     // [N, 3], pre-zeroed
    int n_nodes)
{
    __shared__ float sAcc[RNODES * 3];   // 24 KB
    const int b = blockIdx.x;

    for (int i = threadIdx.x; i < RNODES * 3; i += K2_TPB) sAcc[i] = 0.f;
    __syncthreads();

    unsigned cnt = tails[b];
    if (cnt > CAP) cnt = CAP;
    const nuint2* base  = recs + (size_t)b * CAP;
    const nuint4* base4 = (const nuint4*)base;       // 16 B-aligned (CAP even)

    unsigned npairs = cnt >> 1;
    unsigned i = threadIdx.x;
    // 4x-batched: 4 independent loads in flight before first LDS atomic
    for (; i + 3 * K2_TPB < npairs; i += 4 * K2_TPB) {
        nuint4 p0 = base4[i];
        nuint4 p1 = base4[i + K2_TPB];
        nuint4 p2 = base4[i + 2 * K2_TPB];
        nuint4 p3 = base4[i + 3 * K2_TPB];
        scatter_pair(sAcc, p0);
        scatter_pair(sAcc, p1);
        scatter_pair(sAcc, p2);
        scatter_pair(sAcc, p3);
    }
    for (; i < npairs; i += K2_TPB) {
        nuint4 p = base4[i];
        scatter_pair(sAcc, p);
    }
    if ((cnt & 1u) && threadIdx.x == 0) {             // odd tail record
        nuint2 r = base[cnt - 1];
        unsigned o = (r.y >> 16) * 3;
        atomicAdd(&sAcc[o + 0], __uint_as_float(r.x << 16));
        atomicAdd(&sAcc[o + 1], __uint_as_float(r.x & 0xFFFF0000u));
        atomicAdd(&sAcc[o + 2], __uint_as_float(r.y << 16));
    }
    __syncthreads();

    const int nbase = b * RNODES;
    int limit = n_nodes - nbase;
    if (limit > RNODES) limit = RNODES;
    limit *= 3;
    float* out = KU + (size_t)nbase * 3;
    for (int i2 = threadIdx.x; i2 < limit; i2 += K2_TPB) out[i2] += sAcc[i2];
}

// ---- fallback (round-0 style) --------------------------------------------

__global__ __launch_bounds__(256) void feconv_elem_kernel(
    const float* __restrict__ U, const float* __restrict__ K,
    const int* __restrict__ types, const int* __restrict__ nodIdx,
    float* __restrict__ KU, int n_elems)
{
    int e = blockIdx.x * blockDim.x + threadIdx.x;
    if (e >= n_elems) return;
    int t = types[e];
    const int4* idx4 = (const int4*)(nodIdx + (size_t)e * 8);
    int4 iA = idx4[0], iB = idx4[1];
    int nodes[8] = {iA.x, iA.y, iA.z, iA.w, iB.x, iB.y, iB.z, iB.w};
    float ue[24];
#pragma unroll
    for (int j = 0; j < 8; ++j) {
        const float* up = U + (size_t)nodes[j] * 3;
        ue[3 * j + 0] = up[0]; ue[3 * j + 1] = up[1]; ue[3 * j + 2] = up[2];
    }
    const float* Kt = K + (size_t)t * 576;
#pragma unroll
    for (int i = 0; i < 24; ++i) {
        const float4* row = (const float4*)(Kt + i * 24);
        float acc = 0.f;
#pragma unroll
        for (int q = 0; q < 6; ++q) {
            float4 k = row[q];
            acc += k.x * ue[4 * q + 0] + k.y * ue[4 * q + 1]
                 + k.z * ue[4 * q + 2] + k.w * ue[4 * q + 3];
        }
        atomicAdd(&KU[(size_t)nodes[i / 3] * 3 + (i % 3)], acc);
    }
}

extern "C" void kernel_launch(void* const* d_in, const int* in_sizes, int n_in,
                              void* d_out, int out_size, void* d_ws, size_t ws_size,
                              hipStream_t stream) {
    const float* U      = (const float*)d_in[0];
    const float* Kf     = (const float*)d_in[1];
    const int*   types  = (const int*)d_in[2];
    const int*   nodIdx = (const int*)d_in[3];
    float*       KU     = (float*)d_out;

    const int n_elems = in_sizes[2];
    const int n_nodes = in_sizes[0] / 3;
    const int n_buckets = (n_nodes + RNODES - 1) / RNODES;   // 489 for N=1M

    // ws layout: [0, 4096) tails | [4096, +8B*n_nodes) Ub | then recs
    const size_t ub_off  = 4096;
    const size_t rec_off = ub_off + (((size_t)n_nodes * 8 + 255) & ~255ull);
    const size_t need    = rec_off + (size_t)n_buckets * CAP * 8;

    if (n_buckets <= MAXB && ws_size >= need) {
        unsigned* tails = (unsigned*)d_ws;
        nuint2*   Ub    = (nuint2*)((char*)d_ws + ub_off);
        nuint2*   recs  = (nuint2*)((char*)d_ws + rec_off);

        int gridP = (n_nodes + PREP_TPB - 1) / PREP_TPB;
        pack_u_kernel<<<gridP, PREP_TPB, 0, stream>>>(
            U, Ub, KU, tails, n_nodes, n_buckets);

        size_t lds_bytes = (size_t)NTYPES * KSTRIDE * sizeof(float);  // 148,480
        int grid1 = (n_elems + K1_CHUNK - 1) / K1_CHUNK;               // 245
        feconv_bin_kernel<<<grid1, K1_TPB, lds_bytes, stream>>>(
            Ub, Kf, types, nodIdx, KU, tails, recs, n_elems, n_buckets);
        feconv_acc_kernel<<<n_buckets, K2_TPB, 0, stream>>>(
            recs, tails, KU, n_nodes);
    } else {
        (void)hipMemsetAsync(KU, 0, (size_t)out_size * sizeof(float), stream);
        int block = 256;
        int grid = (n_elems + block - 1) / block;
        feconv_elem_kernel<<<grid, block, 0, stream>>>(
            U, Kf, types, nodIdx, KU, n_elems);
    }
}

// Round 16
// 214.675 us; speedup vs baseline: 1.5213x; 1.5213x over previous
//
#include <hip/hip_runtime.h>

// FEM stiffness matvec KU = sum_e scatter(K_type(e) @ gather(U, e)).
//
// Round 16 = R14's K1 EXACTLY (verified 73 us; R15's type-sort falsified
// the LDS-conflict theory: conflicts -7x yet K1 +110 us from de-coalesced
// nodIdx reads — VMEM gather path is the pin, LDS/VALU are slack) + R15's
// K2 4x-batched pair-loads in isolation (cross-XCD record-fetch latency
// theory for K2's ~55 us).
// Carries (verified): fp32 LDS filters stride 580 b128; EPT=2 with all 16
// Ub gathers issued in pass A; bf16-packed U (8 B slots); 8 B bf16 records
// (local id in high bits); RNODES 2048 / MAXB 512; block-aggregated tail
// reservation; pack kernel zeroes KU+tails; launch_bounds (1024,4)
// (R10: VGPR starvation => scratch-spill disaster).

#define NTYPES    64
#define KSTRIDE   580            // fp32 words per type: 2320 B, 16 B-aligned
#define RSHIFT    11
#define RNODES    2048
#define MAXB      512
#define CAP       10240          // mean 8180/bucket, huge slack (even: 16 B pairs)
#define K1_TPB    1024
#define K1_EPT    2
#define K1_CHUNK  (K1_TPB * K1_EPT)
#define K2_TPB    256
#define PREP_TPB  256

typedef int          nint4  __attribute__((ext_vector_type(4)));
typedef unsigned int nuint2 __attribute__((ext_vector_type(2)));
typedef unsigned int nuint4 __attribute__((ext_vector_type(4)));

__device__ __forceinline__ unsigned bf16_rne(float f) {
    unsigned b = __float_as_uint(f);
    return (b + 0x7FFFu + ((b >> 16) & 1u)) >> 16;
}

// ---- phase 0: pack U -> bf16 triples; zero KU and tails -------------------

__global__ __launch_bounds__(PREP_TPB) void pack_u_kernel(
    const float* __restrict__ U, nuint2* __restrict__ Ub,
    float* __restrict__ KU, unsigned* __restrict__ tails,
    int n_nodes, int n_buckets)
{
    int n = blockIdx.x * PREP_TPB + threadIdx.x;
    if (n < n_buckets) tails[n] = 0;
    if (n >= n_nodes) return;
    const float* up = U + (size_t)n * 3;
    unsigned bx = bf16_rne(up[0]);
    unsigned by = bf16_rne(up[1]);
    unsigned bz = bf16_rne(up[2]);
    nuint2 v = { bx | (by << 16), bz };
    Ub[n] = v;
    KU[3 * n + 0] = 0.f;
    KU[3 * n + 1] = 0.f;
    KU[3 * n + 2] = 0.f;
}

// ---- phase 1: compute + bin (R14-exact) ----------------------------------

__global__ __launch_bounds__(K1_TPB, 4) void feconv_bin_kernel(
    const nuint2* __restrict__ Ub,      // [N] packed bf16 x,y,z
    const float* __restrict__ K,        // [64, 24, 24]
    const int*   __restrict__ types,    // [E]
    const int*   __restrict__ nodIdx,   // [E, 8]
    float*       __restrict__ KU,       // overflow fallback only
    unsigned*    __restrict__ tails,    // [n_buckets]
    nuint2*      __restrict__ recs,     // [n_buckets * CAP]
    int n_elems, int n_buckets)
{
    extern __shared__ float sK[];       // [64 * KSTRIDE] words, per-type rows
    __shared__ unsigned sCnt[MAXB];
    __shared__ unsigned sBase[MAXB];

    for (int w = threadIdx.x; w < NTYPES * 576; w += K1_TPB) {
        int t = w / 576;
        int r = w - t * 576;
        sK[t * KSTRIDE + r] = K[w];
    }
    for (int i = threadIdx.x; i < n_buckets; i += K1_TPB) sCnt[i] = 0;
    __syncthreads();

    const int e0 = blockIdx.x * K1_CHUNK + threadIdx.x;
    int     nodes[K1_EPT][8];
    int     tt[K1_EPT];
    nuint2  uu[K1_EPT][8];              // in-flight packed gathers

    // pass A: COALESCED connectivity + EARLY gather issue + bucket counting
#pragma unroll
    for (int k = 0; k < K1_EPT; ++k) {
        int e = e0 + k * K1_TPB;
        tt[k] = -1;
        if (e < n_elems) {
            tt[k] = __builtin_nontemporal_load(&types[e]);
            const nint4* q = (const nint4*)(nodIdx + (size_t)e * 8);
            nint4 a = __builtin_nontemporal_load(q);
            nint4 b = __builtin_nontemporal_load(q + 1);
            nodes[k][0] = a.x; nodes[k][1] = a.y; nodes[k][2] = a.z; nodes[k][3] = a.w;
            nodes[k][4] = b.x; nodes[k][5] = b.y; nodes[k][6] = b.z; nodes[k][7] = b.w;
#pragma unroll
            for (int j = 0; j < 8; ++j)
                uu[k][j] = Ub[nodes[k][j]];          // issue all 16 gathers now
#pragma unroll
            for (int j = 0; j < 8; ++j)
                atomicAdd(&sCnt[(unsigned)nodes[k][j] >> RSHIFT], 1u);
        }
    }
    __syncthreads();

    // pass B: one global tail reservation per (block, bucket)
    for (int b = threadIdx.x; b < n_buckets; b += K1_TPB) {
        unsigned c = sCnt[b];
        sBase[b] = c ? atomicAdd(&tails[b], c) : 0u;
        sCnt[b] = 0;                     // reuse as local cursor
    }
    __syncthreads();

    // pass C: unpack, matvec via ds_read_b128 filters, write 8 B records
#pragma unroll
    for (int k = 0; k < K1_EPT; ++k) {
        if (tt[k] < 0) continue;

        float ue[24];
#pragma unroll
        for (int j = 0; j < 8; ++j) {
            nuint2 v = uu[k][j];
            ue[3 * j + 0] = __uint_as_float(v.x << 16);
            ue[3 * j + 1] = __uint_as_float(v.x & 0xFFFF0000u);
            ue[3 * j + 2] = __uint_as_float(v.y << 16);
        }

        const float4* Kt4 = (const float4*)(sK + tt[k] * KSTRIDE);
#pragma unroll
        for (int j = 0; j < 8; ++j) {
            float a0 = 0.f, a1 = 0.f, a2 = 0.f;
#pragma unroll
            for (int q = 0; q < 6; ++q) {
                float4 k0 = Kt4[(3 * j + 0) * 6 + q];
                float4 k1 = Kt4[(3 * j + 1) * 6 + q];
                float4 k2 = Kt4[(3 * j + 2) * 6 + q];
                float u0 = ue[4 * q + 0], u1 = ue[4 * q + 1];
                float u2 = ue[4 * q + 2], u3 = ue[4 * q + 3];
                a0 += k0.x * u0 + k0.y * u1 + k0.z * u2 + k0.w * u3;
                a1 += k1.x * u0 + k1.y * u1 + k1.z * u2 + k1.w * u3;
                a2 += k2.x * u0 + k2.y * u1 + k2.z * u2 + k2.w * u3;
            }
            unsigned n = (unsigned)nodes[k][j];
            unsigned b = n >> RSHIFT;
            unsigned pos = sBase[b] + atomicAdd(&sCnt[b], 1u);
            if (pos < CAP) {
                unsigned local = n & (RNODES - 1);
                nuint2 r = { bf16_rne(a0) | (bf16_rne(a1) << 16),
                             bf16_rne(a2) | (local << 16) };
                recs[(size_t)b * CAP + pos] = r;
            } else {  // statistically unreachable; absolute correctness
                atomicAdd(&KU[(size_t)n * 3 + 0], a0);
                atomicAdd(&KU[(size_t)n * 3 + 1], a1);
                atomicAdd(&KU[(size_t)n * 3 + 2], a2);
            }
        }
    }
}

// ---- phase 2: accumulate per bucket (4x-batched MLP) ---------------------

__device__ __forceinline__ void scatter_pair(float* sAcc, nuint4 p) {
    unsigned o0 = (p.y >> 16) * 3;
    atomicAdd(&sAcc[o0 + 0], __uint_as_float(p.x << 16));
    atomicAdd(&sAcc[o0 + 1], __uint_as_float(p.x & 0xFFFF0000u));
    atomicAdd(&sAcc[o0 + 2], __uint_as_float(p.y << 16));
    unsigned o1 = (p.w >> 16) * 3;
    atomicAdd(&sAcc[o1 + 0], __uint_as_float(p.z << 16));
    atomicAdd(&sAcc[o1 + 1], __uint_as_float(p.z & 0xFFFF0000u));
    atomicAdd(&sAcc[o1 + 2], __uint_as_float(p.w << 16));
}

__global__ __launch_bounds__(K2_TPB) void feconv_acc_kernel(
    const nuint2*   __restrict__ recs,
    const unsigned* __restrict__ tails,
    float*          __restrict__ KU,     // [N, 3], pre-zeroed
    int n_nodes)
{
    __shared__ float sAcc[RNODES * 3];   // 24 KB -> ~6 blocks/CU
    const int b = blockIdx.x;

    for (int i = threadIdx.x; i < RNODES * 3; i += K2_TPB) sAcc[i] = 0.f;
    __syncthreads();

    unsigned cnt = tails[b];
    if (cnt > CAP) cnt = CAP;
    const nuint2* base  = recs + (size_t)b * CAP;
    const nuint4* base4 = (const nuint4*)base;       // 16 B-aligned (CAP even)

    unsigned npairs = cnt >> 1;
    unsigned i = threadIdx.x;
    // 4 independent loads in flight before first LDS atomic
    for (; i + 3 * K2_TPB < npairs; i += 4 * K2_TPB) {
        nuint4 p0 = base4[i];
        nuint4 p1 = base4[i + K2_TPB];
        nuint4 p2 = base4[i + 2 * K2_TPB];
        nuint4 p3 = base4[i + 3 * K2_TPB];
        scatter_pair(sAcc, p0);
        scatter_pair(sAcc, p1);
        scatter_pair(sAcc, p2);
        scatter_pair(sAcc, p3);
    }
    for (; i < npairs; i += K2_TPB) {
        nuint4 p = base4[i];
        scatter_pair(sAcc, p);
    }
    if ((cnt & 1u) && threadIdx.x == 0) {             // odd tail record
        nuint2 r = base[cnt - 1];
        unsigned o = (r.y >> 16) * 3;
        atomicAdd(&sAcc[o + 0], __uint_as_float(r.x << 16));
        atomicAdd(&sAcc[o + 1], __uint_as_float(r.x & 0xFFFF0000u));
        atomicAdd(&sAcc[o + 2], __uint_as_float(r.y << 16));
    }
    __syncthreads();

    const int nbase = b * RNODES;
    int limit = n_nodes - nbase;
    if (limit > RNODES) limit = RNODES;
    limit *= 3;
    float* out = KU + (size_t)nbase * 3;
    for (int i2 = threadIdx.x; i2 < limit; i2 += K2_TPB) out[i2] += sAcc[i2];
}

// ---- fallback (round-0 style) --------------------------------------------

__global__ __launch_bounds__(256) void feconv_elem_kernel(
    const float* __restrict__ U, const float* __restrict__ K,
    const int* __restrict__ types, const int* __restrict__ nodIdx,
    float* __restrict__ KU, int n_elems)
{
    int e = blockIdx.x * blockDim.x + threadIdx.x;
    if (e >= n_elems) return;
    int t = types[e];
    const int4* idx4 = (const int4*)(nodIdx + (size_t)e * 8);
    int4 iA = idx4[0], iB = idx4[1];
    int nodes[8] = {iA.x, iA.y, iA.z, iA.w, iB.x, iB.y, iB.z, iB.w};
    float ue[24];
#pragma unroll
    for (int j = 0; j < 8; ++j) {
        const float* up = U + (size_t)nodes[j] * 3;
        ue[3 * j + 0] = up[0]; ue[3 * j + 1] = up[1]; ue[3 * j + 2] = up[2];
    }
    const float* Kt = K + (size_t)t * 576;
#pragma unroll
    for (int i = 0; i < 24; ++i) {
        const float4* row = (const float4*)(Kt + i * 24);
        float acc = 0.f;
#pragma unroll
        for (int q = 0; q < 6; ++q) {
            float4 k = row[q];
            acc += k.x * ue[4 * q + 0] + k.y * ue[4 * q + 1]
                 + k.z * ue[4 * q + 2] + k.w * ue[4 * q + 3];
        }
        atomicAdd(&KU[(size_t)nodes[i / 3] * 3 + (i % 3)], acc);
    }
}

extern "C" void kernel_launch(void* const* d_in, const int* in_sizes, int n_in,
                              void* d_out, int out_size, void* d_ws, size_t ws_size,
                              hipStream_t stream) {
    const float* U      = (const float*)d_in[0];
    const float* Kf     = (const float*)d_in[1];
    const int*   types  = (const int*)d_in[2];
    const int*   nodIdx = (const int*)d_in[3];
    float*       KU     = (float*)d_out;

    const int n_elems = in_sizes[2];
    const int n_nodes = in_sizes[0] / 3;
    const int n_buckets = (n_nodes + RNODES - 1) / RNODES;   // 489 for N=1M

    // ws layout: [0, 4096) tails | [4096, +8B*n_nodes) Ub | then recs
    const size_t ub_off  = 4096;
    const size_t rec_off = ub_off + (((size_t)n_nodes * 8 + 255) & ~255ull);
    const size_t need    = rec_off + (size_t)n_buckets * CAP * 8;

    if (n_buckets <= MAXB && ws_size >= need) {
        unsigned* tails = (unsigned*)d_ws;
        nuint2*   Ub    = (nuint2*)((char*)d_ws + ub_off);
        nuint2*   recs  = (nuint2*)((char*)d_ws + rec_off);

        int gridP = (n_nodes + PREP_TPB - 1) / PREP_TPB;
        pack_u_kernel<<<gridP, PREP_TPB, 0, stream>>>(
            U, Ub, KU, tails, n_nodes, n_buckets);

        size_t lds_bytes = (size_t)NTYPES * KSTRIDE * sizeof(float);  // 148,480
        int grid1 = (n_elems + K1_CHUNK - 1) / K1_CHUNK;               // 245
        feconv_bin_kernel<<<grid1, K1_TPB, lds_bytes, stream>>>(
            Ub, Kf, types, nodIdx, KU, tails, recs, n_elems, n_buckets);
        feconv_acc_kernel<<<n_buckets, K2_TPB, 0, stream>>>(
            recs, tails, KU, n_nodes);
    } else {
        (void)hipMemsetAsync(KU, 0, (size_t)out_size * sizeof(float), stream);
        int block = 256;
        int grid = (n_elems + block - 1) / block;
        feconv_elem_kernel<<<grid, block, 0, stream>>>(
            U, Kf, types, nodIdx, KU, n_elems);
    }
}